// Round 12
// baseline (1084.627 us; speedup 1.0000x reference)
//
#include <hip/hip_runtime.h>

#define BATCH   8
#define NPTS    8192
#define NPOINT  1024
#define NSAMPLE 32
#define CHANC   32
#define OUTC    35          // 3 xyz + 32 point channels
#define R2      0.0625f     // 0.25^2
#define GCTR    32          // centers per ballgroup block
#define CHUNK   2048        // points staged in LDS per chunk

typedef float v2f __attribute__((ext_vector_type(2)));

// DPP helpers --------------------------------------------------------------
template <int CTRL>
__device__ __forceinline__ float dpp_max_step(float v) {
    int r = __builtin_amdgcn_update_dpp(__float_as_int(v), __float_as_int(v),
                                        CTRL, 0xf, 0xf, false);
    return fmaxf(v, __int_as_float(r));
}
#define DPP_ROW_SHR(n)  (0x110 | (n))
#define DPP_BCAST15     0x142
#define DPP_BCAST31     0x143

__device__ __forceinline__ unsigned long long u64max(unsigned long long a,
                                                     unsigned long long b) {
    return a > b ? a : b;
}

// ---------------------------------------------------------------------------
// Kernel 1: furthest point sampling — FROZEN round-9 structure (898 µs,
// VGPR 88, no spill; structural floor for 1-CU-per-batch: restructures
// spill (r6/r8) or add ~250-cyc LDS levels (r7)). One block per batch,
// 512 threads, 16 contiguous pts/thread. Bit-exact fp32 (contract off),
// packed-f32 update, serial inline argmax, DPP wave max + ballot leader,
// packed u64 (val<<32|~idx) partial, one barrier/iter (parity dbuf),
// depth-3 u64 tree scan, coords via XOR-swizzled float4 LDS mirror.
// ---------------------------------------------------------------------------
__global__ __launch_bounds__(512) void fps_kernel(const float* __restrict__ xyz,
                                                  float* __restrict__ new_xyz) {
#pragma clang fp contract(off)
    const int b    = blockIdx.x;
    const int t    = threadIdx.x;
    const int lane = t & 63;
    const int w    = t >> 6;              // wave id, 0..7
    const float* bx = xyz + (size_t)b * NPTS * 3;

    __shared__ float4 pts[NPTS];                    // 128 KB, XOR-swizzled
    __shared__ unsigned long long partial[2][8];

    // thread t owns points j = t*16 + i, i in [0,16): 48 consecutive floats
    v2f px[8], py[8], pz[8], dist[8];
    {
        float f[48];
        float4* fq = (float4*)f;
        const float4* s4 = (const float4*)bx + t * 12;
#pragma unroll
        for (int q = 0; q < 12; ++q) fq[q] = s4[q];
#pragma unroll
        for (int p = 0; p < 8; ++p) {
            px[p] = (v2f){f[6 * p + 0], f[6 * p + 3]};
            py[p] = (v2f){f[6 * p + 1], f[6 * p + 4]};
            pz[p] = (v2f){f[6 * p + 2], f[6 * p + 5]};
            dist[p] = (v2f){1e38f, 1e38f};
        }
#pragma unroll
        for (int i = 0; i < 16; ++i) {
            const int j  = t * 16 + i;
            const int js = j ^ ((j >> 4) & 7);      // bank swizzle
            pts[js] = make_float4(f[3 * i + 0], f[3 * i + 1], f[3 * i + 2], 0.0f);
        }
    }
    __syncthreads();

    // seed: xyz[b, 0]  (swizzle(0) == 0)
    float4 c0 = pts[0];
    float lx = c0.x, ly = c0.y, lz = c0.z;
    if (t == 0) {
        float* o = new_xyz + (size_t)b * NPOINT * 3;
        o[0] = lx; o[1] = ly; o[2] = lz;
    }

    for (int s = 1; s < NPOINT; ++s) {
        // --- packed update + serial inline argmax over 16 points ---
        const v2f lx2 = (v2f){lx, lx};
        const v2f ly2 = (v2f){ly, ly};
        const v2f lz2 = (v2f){lz, lz};
        float bestv = -1.0f;
        int   bi    = 0;
#pragma unroll
        for (int p = 0; p < 8; ++p) {
            const v2f dx = px[p] - lx2;
            const v2f dy = py[p] - ly2;
            const v2f dz = pz[p] - lz2;
            const v2f d2 = (dx * dx + dy * dy) + dz * dz;   // contract off -> exact
            const float d0 = fminf(dist[p].x, d2.x);
            const float d1 = fminf(dist[p].y, d2.y);
            dist[p] = (v2f){d0, d1};
            if (d0 > bestv) { bestv = d0; bi = 2 * p; }     // strict > keeps lowest i
            if (d1 > bestv) { bestv = d1; bi = 2 * p + 1; }
        }
        const int besti = (t << 4) + bi;

        // --- wave64 max via DPP (no LDS) ---
        float v = bestv;
        v = dpp_max_step<DPP_ROW_SHR(1)>(v);
        v = dpp_max_step<DPP_ROW_SHR(2)>(v);
        v = dpp_max_step<DPP_ROW_SHR(4)>(v);
        v = dpp_max_step<DPP_ROW_SHR(8)>(v);
        v = dpp_max_step<DPP_BCAST15>(v);
        v = dpp_max_step<DPP_BCAST31>(v);
        const float smax = __int_as_float(__builtin_amdgcn_readlane(__float_as_int(v), 63));

        // leader lane (lowest lane holding the max == lowest index) writes partial
        const unsigned long long m = __ballot(bestv == smax);
        const int par = s & 1;
        if (lane == (int)__builtin_ctzll(m)) {
            partial[par][w] = ((unsigned long long)__float_as_uint(smax) << 32)
                              | (unsigned)(~besti);
        }
        __syncthreads();

        // --- all lanes scan the 8 partials: depth-3 u64 max tree ---
        const unsigned long long* P = partial[par];
        const unsigned long long a0 = P[0], a1 = P[1], a2 = P[2], a3 = P[3];
        const unsigned long long a4 = P[4], a5 = P[5], a6 = P[6], a7 = P[7];
        const unsigned long long bp =
            u64max(u64max(u64max(a0, a1), u64max(a2, a3)),
                   u64max(u64max(a4, a5), u64max(a6, a7)));
        const int idx = (int)(~(unsigned)bp);
        const int js  = idx ^ ((idx >> 4) & 7);
        const float4 cw = pts[js];              // uniform -> broadcast b128
        lx = cw.x; ly = cw.y; lz = cw.z;
        if (t == 0) {
            float* o = new_xyz + ((size_t)b * NPOINT + s) * 3;
            o[0] = lx; o[1] = ly; o[2] = lz;
        }
    }
}

// ---------------------------------------------------------------------------
// Kernel 2: ball query + grouping, xyz-amortized (round-11 lesson: most
// centers have <32 hits -> full scans; old design re-read 96 KB xyz per
// center = ~800 MB cache traffic = the ~100 µs). Now: 32 centers per block
// (256 blocks), xyz staged into LDS chunk-wise ONCE per block; each wave
// owns 8 centers; round-major/center-minor loop reads each staged point
// once and reuses it 8x in registers. Ordering exact: one wave scans all
// points for its centers in ascending chunk/round/lane order (ballot
// ascending), k-bookkeeping only on hit rounds (__any skip; hits are rare).
// No cross-wave merge. Gather: per wave per center, coalesced stores.
// ---------------------------------------------------------------------------
__global__ __launch_bounds__(256) void ballgroup_kernel(const float* __restrict__ xyz,
                                                        const float* __restrict__ points,
                                                        const float* __restrict__ new_xyz,
                                                        float* __restrict__ out) {
#pragma clang fp contract(off)
    const int tid   = threadIdx.x;
    const int lane  = tid & 63;
    const int w     = tid >> 6;             // wave id, 0..3
    const int cbase = blockIdx.x * GCTR;    // first center of this block
    const int b     = cbase >> 10;          // batch (GCTR divides NPOINT)
    const float* bx = xyz + (size_t)b * NPTS * 3;

    __shared__ float4 spts[CHUNK];          // 32 KB staged points
    __shared__ int    qidx[GCTR][NSAMPLE];  // 4 KB collected indices

    // this wave's 8 centers (coords are wave-uniform)
    float cxv[8], cyv[8], czv[8];
    int   k[8];
#pragma unroll
    for (int c = 0; c < 8; ++c) {
        const float* cen = new_xyz + (size_t)(cbase + w * 8 + c) * 3;
        cxv[c] = cen[0]; cyv[c] = cen[1]; czv[c] = cen[2];
        k[c] = 0;
    }

    for (int chunk = 0; chunk < NPTS; chunk += CHUNK) {
        __syncthreads();                    // protect spts from prior readers
        // stage CHUNK points: 8 per thread, coalesced-ish 12B-stride reads
#pragma unroll
        for (int q = 0; q < CHUNK / 256; ++q) {
            const int p = q * 256 + tid;
            const int j = chunk + p;
            spts[p] = make_float4(bx[j * 3 + 0], bx[j * 3 + 1], bx[j * 3 + 2], 0.0f);
        }
        __syncthreads();

        for (int round = 0; round < CHUNK / 64; ++round) {
            const float4 pt = spts[round * 64 + lane];   // read once, reuse 8x
            const int j = chunk + round * 64 + lane;
#pragma unroll
            for (int c = 0; c < 8; ++c) {
                if (k[c] >= NSAMPLE) continue;           // wave-uniform skip
                const float dx = pt.x - cxv[c];
                const float dy = pt.y - cyv[c];
                const float dz = pt.z - czv[c];
                const float d2 = (dx * dx + dy * dy) + dz * dz;  // contract off
                const bool in = d2 < R2;
                if (__any(in)) {                         // hits are rare
                    const unsigned long long mu = __ballot(in);
                    const int pre = __popcll(mu & ((1ull << lane) - 1ull));
                    if (in && (k[c] + pre) < NSAMPLE)
                        qidx[w * 8 + c][k[c] + pre] = j;
                    k[c] += __popcll(mu);
                }
            }
        }
    }

    // --- gather: each wave writes its 8 centers' 32x35 rows, coalesced ---
    const float* prow = points + (size_t)b * NPTS * CHANC;
#pragma unroll
    for (int c = 0; c < 8; ++c) {
        const int ctr = cbase + w * 8 + c;
        const int kk  = k[c] < NSAMPLE ? k[c] : NSAMPLE; // center itself => kk>=1
        const int firstIdx = qidx[w * 8 + c][0];
        float* o = out + (size_t)ctr * NSAMPLE * OUTC;
        for (int e = lane; e < NSAMPLE * OUTC; e += 64) {
            const int s  = e / OUTC;
            const int ch = e - s * OUTC;
            const int j  = (s < kk) ? qidx[w * 8 + c][s] : firstIdx;
            float v;
            if (ch < 3) {
                const float cc = (ch == 0) ? cxv[c] : (ch == 1) ? cyv[c] : czv[c];
                v = bx[j * 3 + ch] - cc;
            } else {
                v = prow[j * CHANC + (ch - 3)];
            }
            o[e] = v;   // consecutive lanes -> consecutive addresses
        }
    }
}

// ---------------------------------------------------------------------------
extern "C" void kernel_launch(void* const* d_in, const int* in_sizes, int n_in,
                              void* d_out, int out_size, void* d_ws, size_t ws_size,
                              hipStream_t stream) {
    const float* xyz    = (const float*)d_in[0];   // (8, 8192, 3)  fp32
    const float* points = (const float*)d_in[1];   // (8, 8192, 32) fp32
    float* new_xyz    = (float*)d_out;                         // (8,1024,3)
    float* new_points = new_xyz + (size_t)BATCH * NPOINT * 3;  // (8,1024,32,35)

    fps_kernel<<<BATCH, 512, 0, stream>>>(xyz, new_xyz);
    ballgroup_kernel<<<(BATCH * NPOINT) / GCTR, 256, 0, stream>>>(xyz, points, new_xyz, new_points);
}

// Round 13
// 1033.719 us; speedup vs baseline: 1.0492x; 1.0492x over previous
//
#include <hip/hip_runtime.h>

#define BATCH   8
#define NPTS    8192
#define NPOINT  1024
#define NSAMPLE 32
#define CHANC   32
#define OUTC    35          // 3 xyz + 32 point channels
#define R2      0.0625f     // 0.25^2
#define GCTR    16          // centers per ballgroup block (r12: 32 -> occupancy cliff)
#define CPW     4           // centers per wave
#define CHUNK   2048        // points staged in LDS per chunk

typedef float v2f __attribute__((ext_vector_type(2)));

// DPP helpers --------------------------------------------------------------
template <int CTRL>
__device__ __forceinline__ float dpp_max_step(float v) {
    int r = __builtin_amdgcn_update_dpp(__float_as_int(v), __float_as_int(v),
                                        CTRL, 0xf, 0xf, false);
    return fmaxf(v, __int_as_float(r));
}
#define DPP_ROW_SHR(n)  (0x110 | (n))
#define DPP_BCAST15     0x142
#define DPP_BCAST31     0x143

__device__ __forceinline__ unsigned long long u64max(unsigned long long a,
                                                     unsigned long long b) {
    return a > b ? a : b;
}

// ---------------------------------------------------------------------------
// Kernel 1: furthest point sampling — FROZEN round-9 structure (898 µs,
// VGPR 88, no spill; structural floor for 1-CU-per-batch: restructures
// spill (r6/r8) or add ~250-cyc LDS levels (r7)). One block per batch,
// 512 threads, 16 contiguous pts/thread. Bit-exact fp32 (contract off),
// packed-f32 update, serial inline argmax, DPP wave max + ballot leader,
// packed u64 (val<<32|~idx) partial, one barrier/iter (parity dbuf),
// depth-3 u64 tree scan, coords via XOR-swizzled float4 LDS mirror.
// ---------------------------------------------------------------------------
__global__ __launch_bounds__(512) void fps_kernel(const float* __restrict__ xyz,
                                                  float* __restrict__ new_xyz) {
#pragma clang fp contract(off)
    const int b    = blockIdx.x;
    const int t    = threadIdx.x;
    const int lane = t & 63;
    const int w    = t >> 6;              // wave id, 0..7
    const float* bx = xyz + (size_t)b * NPTS * 3;

    __shared__ float4 pts[NPTS];                    // 128 KB, XOR-swizzled
    __shared__ unsigned long long partial[2][8];

    // thread t owns points j = t*16 + i, i in [0,16): 48 consecutive floats
    v2f px[8], py[8], pz[8], dist[8];
    {
        float f[48];
        float4* fq = (float4*)f;
        const float4* s4 = (const float4*)bx + t * 12;
#pragma unroll
        for (int q = 0; q < 12; ++q) fq[q] = s4[q];
#pragma unroll
        for (int p = 0; p < 8; ++p) {
            px[p] = (v2f){f[6 * p + 0], f[6 * p + 3]};
            py[p] = (v2f){f[6 * p + 1], f[6 * p + 4]};
            pz[p] = (v2f){f[6 * p + 2], f[6 * p + 5]};
            dist[p] = (v2f){1e38f, 1e38f};
        }
#pragma unroll
        for (int i = 0; i < 16; ++i) {
            const int j  = t * 16 + i;
            const int js = j ^ ((j >> 4) & 7);      // bank swizzle
            pts[js] = make_float4(f[3 * i + 0], f[3 * i + 1], f[3 * i + 2], 0.0f);
        }
    }
    __syncthreads();

    // seed: xyz[b, 0]  (swizzle(0) == 0)
    float4 c0 = pts[0];
    float lx = c0.x, ly = c0.y, lz = c0.z;
    if (t == 0) {
        float* o = new_xyz + (size_t)b * NPOINT * 3;
        o[0] = lx; o[1] = ly; o[2] = lz;
    }

    for (int s = 1; s < NPOINT; ++s) {
        // --- packed update + serial inline argmax over 16 points ---
        const v2f lx2 = (v2f){lx, lx};
        const v2f ly2 = (v2f){ly, ly};
        const v2f lz2 = (v2f){lz, lz};
        float bestv = -1.0f;
        int   bi    = 0;
#pragma unroll
        for (int p = 0; p < 8; ++p) {
            const v2f dx = px[p] - lx2;
            const v2f dy = py[p] - ly2;
            const v2f dz = pz[p] - lz2;
            const v2f d2 = (dx * dx + dy * dy) + dz * dz;   // contract off -> exact
            const float d0 = fminf(dist[p].x, d2.x);
            const float d1 = fminf(dist[p].y, d2.y);
            dist[p] = (v2f){d0, d1};
            if (d0 > bestv) { bestv = d0; bi = 2 * p; }     // strict > keeps lowest i
            if (d1 > bestv) { bestv = d1; bi = 2 * p + 1; }
        }
        const int besti = (t << 4) + bi;

        // --- wave64 max via DPP (no LDS) ---
        float v = bestv;
        v = dpp_max_step<DPP_ROW_SHR(1)>(v);
        v = dpp_max_step<DPP_ROW_SHR(2)>(v);
        v = dpp_max_step<DPP_ROW_SHR(4)>(v);
        v = dpp_max_step<DPP_ROW_SHR(8)>(v);
        v = dpp_max_step<DPP_BCAST15>(v);
        v = dpp_max_step<DPP_BCAST31>(v);
        const float smax = __int_as_float(__builtin_amdgcn_readlane(__float_as_int(v), 63));

        // leader lane (lowest lane holding the max == lowest index) writes partial
        const unsigned long long m = __ballot(bestv == smax);
        const int par = s & 1;
        if (lane == (int)__builtin_ctzll(m)) {
            partial[par][w] = ((unsigned long long)__float_as_uint(smax) << 32)
                              | (unsigned)(~besti);
        }
        __syncthreads();

        // --- all lanes scan the 8 partials: depth-3 u64 max tree ---
        const unsigned long long* P = partial[par];
        const unsigned long long a0 = P[0], a1 = P[1], a2 = P[2], a3 = P[3];
        const unsigned long long a4 = P[4], a5 = P[5], a6 = P[6], a7 = P[7];
        const unsigned long long bp =
            u64max(u64max(u64max(a0, a1), u64max(a2, a3)),
                   u64max(u64max(a4, a5), u64max(a6, a7)));
        const int idx = (int)(~(unsigned)bp);
        const int js  = idx ^ ((idx >> 4) & 7);
        const float4 cw = pts[js];              // uniform -> broadcast b128
        lx = cw.x; ly = cw.y; lz = cw.z;
        if (t == 0) {
            float* o = new_xyz + ((size_t)b * NPOINT + s) * 3;
            o[0] = lx; o[1] = ly; o[2] = lz;
        }
    }
}

// ---------------------------------------------------------------------------
// Kernel 2: ball query + grouping, xyz-amortized WITH occupancy (r12 lesson:
// GCTR=32 -> 256 blocks = 1 wave/SIMD = exposed latency everywhere).
// GCTR=16, 256 threads: 512 blocks = 2 blocks/CU, 8 waves/CU. xyz staged
// into LDS chunk-wise once per block (16x traffic cut vs per-center scans);
// each wave owns 4 centers, reads each staged point once, reuses 4x in
// registers. Ordering exact (ascending chunk/round/lane; ballot ascending);
// bookkeeping only on hit rounds (__any skip). No cross-wave merge.
// ---------------------------------------------------------------------------
__global__ __launch_bounds__(256) void ballgroup_kernel(const float* __restrict__ xyz,
                                                        const float* __restrict__ points,
                                                        const float* __restrict__ new_xyz,
                                                        float* __restrict__ out) {
#pragma clang fp contract(off)
    const int tid   = threadIdx.x;
    const int lane  = tid & 63;
    const int w     = tid >> 6;             // wave id, 0..3
    const int cbase = blockIdx.x * GCTR;    // first center of this block
    const int b     = cbase >> 10;          // batch (GCTR divides NPOINT)
    const float* bx = xyz + (size_t)b * NPTS * 3;

    __shared__ float4 spts[CHUNK];          // 32 KB staged points
    __shared__ int    qidx[GCTR][NSAMPLE];  // 2 KB collected indices

    // this wave's 4 centers (coords are wave-uniform)
    float cxv[CPW], cyv[CPW], czv[CPW];
    int   k[CPW];
#pragma unroll
    for (int c = 0; c < CPW; ++c) {
        const float* cen = new_xyz + (size_t)(cbase + w * CPW + c) * 3;
        cxv[c] = cen[0]; cyv[c] = cen[1]; czv[c] = cen[2];
        k[c] = 0;
    }

    for (int chunk = 0; chunk < NPTS; chunk += CHUNK) {
        __syncthreads();                    // protect spts from prior readers
        // stage CHUNK points: 8 per thread
#pragma unroll
        for (int q = 0; q < CHUNK / 256; ++q) {
            const int p = q * 256 + tid;
            const int j = chunk + p;
            spts[p] = make_float4(bx[j * 3 + 0], bx[j * 3 + 1], bx[j * 3 + 2], 0.0f);
        }
        __syncthreads();

        for (int round = 0; round < CHUNK / 64; ++round) {
            const float4 pt = spts[round * 64 + lane];   // read once, reuse 4x
            const int j = chunk + round * 64 + lane;
#pragma unroll
            for (int c = 0; c < CPW; ++c) {
                if (k[c] >= NSAMPLE) continue;           // wave-uniform skip
                const float dx = pt.x - cxv[c];
                const float dy = pt.y - cyv[c];
                const float dz = pt.z - czv[c];
                const float d2 = (dx * dx + dy * dy) + dz * dz;  // contract off
                const bool in = d2 < R2;
                if (__any(in)) {                         // hits are rare
                    const unsigned long long mu = __ballot(in);
                    const int pre = __popcll(mu & ((1ull << lane) - 1ull));
                    if (in && (k[c] + pre) < NSAMPLE)
                        qidx[w * CPW + c][k[c] + pre] = j;
                    k[c] += __popcll(mu);
                }
            }
        }
    }

    // --- gather: each wave writes its 4 centers' 32x35 rows, coalesced ---
    const float* prow = points + (size_t)b * NPTS * CHANC;
#pragma unroll
    for (int c = 0; c < CPW; ++c) {
        const int ctr = cbase + w * CPW + c;
        const int kk  = k[c] < NSAMPLE ? k[c] : NSAMPLE; // center itself => kk>=1
        const int firstIdx = qidx[w * CPW + c][0];
        float* o = out + (size_t)ctr * NSAMPLE * OUTC;
        for (int e = lane; e < NSAMPLE * OUTC; e += 64) {
            const int s  = e / OUTC;
            const int ch = e - s * OUTC;
            const int j  = (s < kk) ? qidx[w * CPW + c][s] : firstIdx;
            float v;
            if (ch < 3) {
                const float cc = (ch == 0) ? cxv[c] : (ch == 1) ? cyv[c] : czv[c];
                v = bx[j * 3 + ch] - cc;
            } else {
                v = prow[j * CHANC + (ch - 3)];
            }
            o[e] = v;   // consecutive lanes -> consecutive addresses
        }
    }
}

// ---------------------------------------------------------------------------
extern "C" void kernel_launch(void* const* d_in, const int* in_sizes, int n_in,
                              void* d_out, int out_size, void* d_ws, size_t ws_size,
                              hipStream_t stream) {
    const float* xyz    = (const float*)d_in[0];   // (8, 8192, 3)  fp32
    const float* points = (const float*)d_in[1];   // (8, 8192, 32) fp32
    float* new_xyz    = (float*)d_out;                         // (8,1024,3)
    float* new_points = new_xyz + (size_t)BATCH * NPOINT * 3;  // (8,1024,32,35)

    fps_kernel<<<BATCH, 512, 0, stream>>>(xyz, new_xyz);
    ballgroup_kernel<<<(BATCH * NPOINT) / GCTR, 256, 0, stream>>>(xyz, points, new_xyz, new_points);
}

// Round 14
// 992.949 us; speedup vs baseline: 1.0923x; 1.0411x over previous
//
#include <hip/hip_runtime.h>

#define BATCH   8
#define NPTS    8192
#define NPOINT  1024
#define NSAMPLE 32
#define CHANC   32
#define OUTC    35          // 3 xyz + 32 point channels
#define R2      0.0625f     // 0.25^2

typedef float v2f __attribute__((ext_vector_type(2)));

// DPP helpers --------------------------------------------------------------
template <int CTRL>
__device__ __forceinline__ float dpp_max_step(float v) {
    int r = __builtin_amdgcn_update_dpp(__float_as_int(v), __float_as_int(v),
                                        CTRL, 0xf, 0xf, false);
    return fmaxf(v, __int_as_float(r));
}
#define DPP_ROW_SHR(n)  (0x110 | (n))
#define DPP_BCAST15     0x142
#define DPP_BCAST31     0x143

__device__ __forceinline__ unsigned long long u64max(unsigned long long a,
                                                     unsigned long long b) {
    return a > b ? a : b;
}

// ---------------------------------------------------------------------------
// Kernel 1: furthest point sampling — FROZEN round-9 structure (898 µs) +
// final dump of the LDS float4 mirror to d_ws (packed xyz for ballgroup's
// coalesced scan; ~2 µs of coalesced stores). One block per batch, 512
// threads, 16 contiguous pts/thread. Bit-exact fp32 (contract off),
// packed-f32 update, serial inline argmax, DPP wave max + ballot leader,
// packed u64 (val<<32|~idx) partial, one barrier/iter (parity dbuf),
// depth-3 u64 tree scan, coords via XOR-swizzled float4 LDS mirror.
// ---------------------------------------------------------------------------
__global__ __launch_bounds__(512) void fps_kernel(const float* __restrict__ xyz,
                                                  float* __restrict__ new_xyz,
                                                  float4* __restrict__ xyz4) {
#pragma clang fp contract(off)
    const int b    = blockIdx.x;
    const int t    = threadIdx.x;
    const int lane = t & 63;
    const int w    = t >> 6;              // wave id, 0..7
    const float* bx = xyz + (size_t)b * NPTS * 3;

    __shared__ float4 pts[NPTS];                    // 128 KB, XOR-swizzled
    __shared__ unsigned long long partial[2][8];

    // thread t owns points j = t*16 + i, i in [0,16): 48 consecutive floats
    v2f px[8], py[8], pz[8], dist[8];
    {
        float f[48];
        float4* fq = (float4*)f;
        const float4* s4 = (const float4*)bx + t * 12;
#pragma unroll
        for (int q = 0; q < 12; ++q) fq[q] = s4[q];
#pragma unroll
        for (int p = 0; p < 8; ++p) {
            px[p] = (v2f){f[6 * p + 0], f[6 * p + 3]};
            py[p] = (v2f){f[6 * p + 1], f[6 * p + 4]};
            pz[p] = (v2f){f[6 * p + 2], f[6 * p + 5]};
            dist[p] = (v2f){1e38f, 1e38f};
        }
#pragma unroll
        for (int i = 0; i < 16; ++i) {
            const int j  = t * 16 + i;
            const int js = j ^ ((j >> 4) & 7);      // bank swizzle
            pts[js] = make_float4(f[3 * i + 0], f[3 * i + 1], f[3 * i + 2], 0.0f);
        }
    }
    __syncthreads();

    // seed: xyz[b, 0]  (swizzle(0) == 0)
    float4 c0 = pts[0];
    float lx = c0.x, ly = c0.y, lz = c0.z;
    if (t == 0) {
        float* o = new_xyz + (size_t)b * NPOINT * 3;
        o[0] = lx; o[1] = ly; o[2] = lz;
    }

    for (int s = 1; s < NPOINT; ++s) {
        // --- packed update + serial inline argmax over 16 points ---
        const v2f lx2 = (v2f){lx, lx};
        const v2f ly2 = (v2f){ly, ly};
        const v2f lz2 = (v2f){lz, lz};
        float bestv = -1.0f;
        int   bi    = 0;
#pragma unroll
        for (int p = 0; p < 8; ++p) {
            const v2f dx = px[p] - lx2;
            const v2f dy = py[p] - ly2;
            const v2f dz = pz[p] - lz2;
            const v2f d2 = (dx * dx + dy * dy) + dz * dz;   // contract off -> exact
            const float d0 = fminf(dist[p].x, d2.x);
            const float d1 = fminf(dist[p].y, d2.y);
            dist[p] = (v2f){d0, d1};
            if (d0 > bestv) { bestv = d0; bi = 2 * p; }     // strict > keeps lowest i
            if (d1 > bestv) { bestv = d1; bi = 2 * p + 1; }
        }
        const int besti = (t << 4) + bi;

        // --- wave64 max via DPP (no LDS) ---
        float v = bestv;
        v = dpp_max_step<DPP_ROW_SHR(1)>(v);
        v = dpp_max_step<DPP_ROW_SHR(2)>(v);
        v = dpp_max_step<DPP_ROW_SHR(4)>(v);
        v = dpp_max_step<DPP_ROW_SHR(8)>(v);
        v = dpp_max_step<DPP_BCAST15>(v);
        v = dpp_max_step<DPP_BCAST31>(v);
        const float smax = __int_as_float(__builtin_amdgcn_readlane(__float_as_int(v), 63));

        // leader lane (lowest lane holding the max == lowest index) writes partial
        const unsigned long long m = __ballot(bestv == smax);
        const int par = s & 1;
        if (lane == (int)__builtin_ctzll(m)) {
            partial[par][w] = ((unsigned long long)__float_as_uint(smax) << 32)
                              | (unsigned)(~besti);
        }
        __syncthreads();

        // --- all lanes scan the 8 partials: depth-3 u64 max tree ---
        const unsigned long long* P = partial[par];
        const unsigned long long a0 = P[0], a1 = P[1], a2 = P[2], a3 = P[3];
        const unsigned long long a4 = P[4], a5 = P[5], a6 = P[6], a7 = P[7];
        const unsigned long long bp =
            u64max(u64max(u64max(a0, a1), u64max(a2, a3)),
                   u64max(u64max(a4, a5), u64max(a6, a7)));
        const int idx = (int)(~(unsigned)bp);
        const int js  = idx ^ ((idx >> 4) & 7);
        const float4 cw = pts[js];              // uniform -> broadcast b128
        lx = cw.x; ly = cw.y; lz = cw.z;
        if (t == 0) {
            float* o = new_xyz + ((size_t)b * NPOINT + s) * 3;
            o[0] = lx; o[1] = ly; o[2] = lz;
        }
    }

    // --- dump packed float4 xyz to workspace (coalesced 1KB/wave stores) ---
    float4* wb = xyz4 + (size_t)b * NPTS;
#pragma unroll
    for (int q = 0; q < 16; ++q) {
        const int p  = q * 512 + t;
        const int ps = p ^ ((p >> 4) & 7);      // un-swizzle
        wb[p] = pts[ps];
    }
}

// ---------------------------------------------------------------------------
// Kernel 2: ball query + grouping — r11 quarter shape (best measured) with
// COALESCED float4 scan loads from the packed xyz4 workspace (round-13
// analysis: stride-12 dword scan loads are 64-lane gathers, TA-throughput
// bound ~80 µs; packed dwordx4 is 1 coalesced instr per point, TA /4).
// One block (4 waves) per center; wave r scans quarter r in 8 superrounds
// of 256 pts (loads hoisted, ballot bookkeeping after, one exit check).
// Quarter results prefix-merged (exact first-32-ascending + first-hit pad).
// Gather: 256 threads over 32x35, coalesced stores.
// ---------------------------------------------------------------------------
__global__ __launch_bounds__(256) void ballgroup_kernel(const float4* __restrict__ xyz4,
                                                        const float* __restrict__ points,
                                                        const float* __restrict__ new_xyz,
                                                        float* __restrict__ out) {
#pragma clang fp contract(off)
    const int tid  = threadIdx.x;
    const int lane = tid & 63;
    const int r    = tid >> 6;            // wave id = quarter id, 0..3
    const int gw   = blockIdx.x;          // center id, 0..8191
    const int b    = gw >> 10;

    const float4* bx4 = xyz4 + (size_t)b * NPTS;
    const float*  cen = new_xyz + (size_t)gw * 3;
    const float cx = cen[0], cy = cen[1], cz = cen[2];

    __shared__ int qidx[4][NSAMPLE];
    __shared__ int qcnt[4];

    // --- scan this wave's quarter: 2048 pts, 8 superrounds of 256 ---
    int k = 0;
    const int qbase = r << 11;
    for (int base = qbase; base < qbase + 2048; base += 256) {
        // phase 1: hoist 4 coalesced dwordx4 loads (independent)
        float4 p4[4];
#pragma unroll
        for (int u = 0; u < 4; ++u) p4[u] = bx4[base + u * 64 + lane];
        // phase 2: distances + masks (no memory)
        bool in[4];
#pragma unroll
        for (int u = 0; u < 4; ++u) {
            const float dx = p4[u].x - cx;
            const float dy = p4[u].y - cy;
            const float dz = p4[u].z - cz;
            const float d2 = (dx * dx + dy * dy) + dz * dz;   // contract off
            in[u] = d2 < R2;
        }
        // phase 3: serial bookkeeping (no loads on chain)
#pragma unroll
        for (int u = 0; u < 4; ++u) {
            const unsigned long long mu = __ballot(in[u]);
            const int pre = __popcll(mu & ((1ull << lane) - 1ull));
            if (in[u] && (k + pre) < NSAMPLE) qidx[r][k + pre] = base + u * 64 + lane;
            k += __popcll(mu);
        }
        if (k >= NSAMPLE) break;          // one exit check per superround
    }
    if (k > NSAMPLE) k = NSAMPLE;
    if (lane == 0) qcnt[r] = k;
    __syncthreads();

    // --- prefix-merge: first NSAMPLE of the concatenated quarters ---
    const int c0n = qcnt[0], c1n = qcnt[1], c2n = qcnt[2], c3n = qcnt[3];
    const int o1 = c0n, o2 = c0n + c1n, o3 = o2 + c2n;
    const int total = o3 + c3n;
    const int kk = total < NSAMPLE ? total : NSAMPLE;
    // first hit overall = first entry of the first nonempty quarter
    // (center's own point has d2==0, so total >= 1 always)
    const int r0 = (c0n > 0) ? 0 : (c1n > 0) ? 1 : (c2n > 0) ? 2 : 3;
    const int firstIdx = qidx[r0][0];

    // --- gather: 32x35 output elems across 256 threads, coalesced ---
    float*       o    = out + (size_t)gw * NSAMPLE * OUTC;
    const float* prow = points + (size_t)b * NPTS * CHANC;
    for (int e = tid; e < NSAMPLE * OUTC; e += 256) {
        const int s = e / OUTC;
        const int c = e - s * OUTC;
        int j;
        if (s < kk) {
            const int rr  = (int)(s >= o1) + (int)(s >= o2) + (int)(s >= o3);
            const int off = (rr == 0) ? 0 : (rr == 1) ? o1 : (rr == 2) ? o2 : o3;
            j = qidx[rr][s - off];
        } else {
            j = firstIdx;
        }
        float v;
        if (c < 3) {
            const float4 pj = bx4[j];
            const float pv = (c == 0) ? pj.x : (c == 1) ? pj.y : pj.z;
            const float cc = (c == 0) ? cx : (c == 1) ? cy : cz;
            v = pv - cc;
        } else {
            v = prow[j * CHANC + (c - 3)];
        }
        o[e] = v;   // consecutive lanes -> consecutive addresses (coalesced)
    }
}

// ---------------------------------------------------------------------------
extern "C" void kernel_launch(void* const* d_in, const int* in_sizes, int n_in,
                              void* d_out, int out_size, void* d_ws, size_t ws_size,
                              hipStream_t stream) {
    const float* xyz    = (const float*)d_in[0];   // (8, 8192, 3)  fp32
    const float* points = (const float*)d_in[1];   // (8, 8192, 32) fp32
    float* new_xyz    = (float*)d_out;                         // (8,1024,3)
    float* new_points = new_xyz + (size_t)BATCH * NPOINT * 3;  // (8,1024,32,35)
    float4* xyz4      = (float4*)d_ws;                         // 512 KB packed

    fps_kernel<<<BATCH, 512, 0, stream>>>(xyz, new_xyz, xyz4);
    ballgroup_kernel<<<BATCH * NPOINT, 256, 0, stream>>>(xyz4, points, new_xyz, new_points);
}